// Round 5
// baseline (375.243 us; speedup 1.0000x reference)
//
#include <hip/hip_runtime.h>

// Cost volume: B=4, C=32, H=256, W=256, D=9, G=8, cpg=4
// y offset is 0 => bilinear collapses to 1-D lerp along x; all taps for
// lane w lie in [w-2, w+2].
// R5: latency fix. R4 was stalled on 14 per-lane global gathers per pair
// (~3 VALU addressing each + ~200cyc L2 latency, occupancy 25%). Replace
// with LDS-staged zero-padded rows via global_load_lds width=16:
//  - coalesced async stage of 8 ls + 8 rs rows (one barrier total)
//  - 4-float zero pads each side => OOB taps read 0, validity logic gone
//  - taps are ds_read_b32 with channel offset folded into the imm field
//    => ~zero addressing VALU in the inner loop
//  - inner math identical to R4 (per-d 3-tap lerp weights, packed fp32)

#define B_ 4
#define C_ 32
#define H_ 256
#define W_ 256
#define D_ 9
#define G_ 8
#define HW_ (H_ * W_)
#define RSTRIDE 264   // 4 pad + 256 data + 4 pad floats; 1056 B (16B-aligned)

typedef float v2f __attribute__((ext_vector_type(2)));

__global__ __launch_bounds__(256, 4) void cost_volume_kernel(
    const float* __restrict__ fref,
    const float* __restrict__ fls,
    const float* __restrict__ frs,
    const float* __restrict__ disp0,
    float* __restrict__ out)
{
    const float res[D_] = {-0.4f, -0.3f, -0.2f, -0.1f, 0.0f,
                            0.1f,  0.2f,  0.3f,  0.4f};
    __shared__ float smem[16 * RSTRIDE];   // rows 0-7: ls ch0-7, 8-15: rs ch0-7

    int g2 = blockIdx.x & 3;               // which pair of groups
    int t  = blockIdx.x >> 2;
    int h  = t & (H_ - 1);
    int b  = t >> 8;
    int w  = threadIdx.x;
    int lane = w & 63;
    int wave = w >> 6;

    size_t base = (size_t)b * C_ * HW_ + (size_t)h * W_ + (size_t)(g2 * 8) * HW_;
    const float* pref = fref + base;
    const float* pls  = fls  + base;
    const float* prs  = frs  + base;

    // --- async stage 16 rows (each wave stages 4); lane-ordered 16B chunks.
    #pragma unroll
    for (int rr = 0; rr < 4; ++rr) {
        int r  = wave * 4 + rr;
        int ch = r & 7;
        const float* grow = ((r < 8) ? pls : prs) + (size_t)ch * HW_ + lane * 4;
        float* lrow = smem + r * RSTRIDE + 4 + lane * 4;
        __builtin_amdgcn_global_load_lds(
            (__attribute__((address_space(1))) unsigned int*)(unsigned long long)grow,
            (__attribute__((address_space(3))) unsigned int*)lrow,
            16, 0, 0);
    }
    // zero the pads: 16 rows x 8 pad floats
    if (w < 128) {
        int r = w >> 3;
        int k = w & 7;
        smem[r * RSTRIDE + ((k < 4) ? k : (256 + k))] = 0.0f;
    }

    // --- per-thread setup overlaps the staging loads
    float dbase = disp0[((size_t)b * H_ + h) * W_ + w];

    // floor(xl_d) spans <= 2 consecutive ints over d (res span 0.8 < 1);
    // min at d=0 (left) / d=8 (right). Verified on HW in R2-R4.
    int i0l = (int)floorf((float)w + (dbase + res[0]));
    int i0r = (int)floorf((float)w - (dbase + res[8]));

    // Pure lerp weights (zeros-padding handled by LDS pads).
    float la[D_], lb[D_], lc[D_];
    float ra[D_], rb[D_], rc[D_];
    #pragma unroll
    for (int d = 0; d < D_; ++d) {
        float disp = dbase + res[d];

        float xl = (float)w + disp;
        float fl = floorf(xl);
        float f1 = xl - fl;
        float f0 = 1.0f - f1;
        bool jl = ((int)fl != i0l);        // cell offset 0 or 1
        la[d] = jl ? 0.0f : f0;
        lb[d] = jl ? f0 : f1;
        lc[d] = jl ? f1 : 0.0f;

        float xr = (float)w - disp;
        float fx = floorf(xr);
        float u1 = xr - fx;
        float u0 = 1.0f - u1;
        bool jr = ((int)fx != i0r);
        ra[d] = jr ? 0.0f : u0;
        rb[d] = jr ? u0 : u1;
        rc[d] = jr ? u1 : 0.0f;
    }

    __syncthreads();   // drains global_load_lds (vmcnt) + pad writes

    int idxL = 4 + i0l;   // LDS float index of left tap 0 (in [2,261])
    int idxR = 4 + i0r;

    size_t obase = ((size_t)b * G_ + g2 * 2) * D_ * HW_ + (size_t)h * W_ + w;

    #pragma unroll 1
    for (int gc = 0; gc < 2; ++gc) {
        v2f acc[D_];
        #pragma unroll
        for (int d = 0; d < D_; ++d) acc[d] = (v2f)(0.0f);

        #pragma unroll
        for (int p = 0; p < 2; ++p) {
            int c0 = gc * 4 + p * 2;   // channel pair within the block's 8

            v2f fr = { pref[(size_t)c0 * HW_ + w],
                       pref[(size_t)(c0 + 1) * HW_ + w] };

            // taps: channel offset is a compile-time literal (folded into
            // the ds_read immediate); vaddr is idxL/idxR only.
            v2f t0 = { smem[ c0      * RSTRIDE + idxL    ],
                       smem[(c0 + 1) * RSTRIDE + idxL    ] };
            v2f t1 = { smem[ c0      * RSTRIDE + idxL + 1],
                       smem[(c0 + 1) * RSTRIDE + idxL + 1] };
            v2f t2 = { smem[ c0      * RSTRIDE + idxL + 2],
                       smem[(c0 + 1) * RSTRIDE + idxL + 2] };
            v2f u0 = { smem[(8 + c0    ) * RSTRIDE + idxR    ],
                       smem[(8 + c0 + 1) * RSTRIDE + idxR    ] };
            v2f u1 = { smem[(8 + c0    ) * RSTRIDE + idxR + 1],
                       smem[(8 + c0 + 1) * RSTRIDE + idxR + 1] };
            v2f u2 = { smem[(8 + c0    ) * RSTRIDE + idxR + 2],
                       smem[(8 + c0 + 1) * RSTRIDE + idxR + 2] };

            v2f fr2 = fr * fr;

            #pragma unroll
            for (int d = 0; d < D_; ++d) {
                v2f wl = t0 * la[d] + t1 * lb[d] + t2 * lc[d];
                v2f wr = u0 * ra[d] + u1 * rb[d] + u2 * rc[d];
                v2f s  = wl + wr + fr;
                v2f q  = __builtin_elementwise_fma(
                             wl, wl, __builtin_elementwise_fma(wr, wr, fr2));
                acc[d] = __builtin_elementwise_fma(
                             s * s, (v2f)(-1.0f / 3.0f), acc[d] + q);
            }
        }

        // q - s^2/3 = 3*var_c; summed over 4 ch -> mean(var) = acc/12.
        #pragma unroll
        for (int d = 0; d < D_; ++d) {
            out[obase + (size_t)(gc * D_ + d) * HW_] =
                (acc[d].x + acc[d].y) * (1.0f / 12.0f);
        }
    }
}

extern "C" void kernel_launch(void* const* d_in, const int* in_sizes, int n_in,
                              void* d_out, int out_size, void* d_ws, size_t ws_size,
                              hipStream_t stream) {
    const float* fref  = (const float*)d_in[0];
    const float* fls   = (const float*)d_in[1];
    const float* frs   = (const float*)d_in[2];
    const float* disp0 = (const float*)d_in[3];
    float* out = (float*)d_out;

    dim3 grid(B_ * H_ * 4);
    dim3 block(W_);
    cost_volume_kernel<<<grid, block, 0, stream>>>(fref, fls, frs, disp0, out);
}